// Round 1
// baseline (306.474 us; speedup 1.0000x reference)
//
#include <hip/hip_runtime.h>

#define BB 16
#define MM 1024
#define NN 2048
#define MAXD 64
#define NITER 5

// Build per-row edge lists from dense H. Order within a row is arbitrary
// (atomicAdd append) — all downstream reductions are order-independent.
__global__ void build_rows(const int* __restrict__ H, int* __restrict__ row_deg,
                           int* __restrict__ row_cols) {
    int idx = blockIdx.x * blockDim.x + threadIdx.x;
    if (idx >= MM * NN) return;
    int m = idx >> 11;          // / NN
    int c = idx & (NN - 1);     // % NN
    if (H[idx] != 0) {
        int j = atomicAdd(&row_deg[m], 1);
        if (j < MAXD) row_cols[m * MAXD + j] = c;
    }
}

// One thread per (b, m) check node. soft_new must be pre-initialized to
// soft_input; this kernel scatters cv messages into it.
// Every block handles 256 consecutive m for a single b (M=1024, blockDim=256),
// so cols 0/1 (present in EVERY row -> worst atomic contention) are
// block-reduced in LDS and flushed with one atomic each.
__global__ void check_pass(const float* __restrict__ soft_old,
                           float* __restrict__ soft_new,
                           const int* __restrict__ row_deg,
                           const int* __restrict__ row_cols,
                           const float* __restrict__ wptr) {
    int tid = blockIdx.x * blockDim.x + threadIdx.x;   // b*M + m
    int b = tid >> 10;                                  // / MM
    int m = tid & (MM - 1);
    float norm = log1pf(expf(wptr[0]));                 // softplus(w)

    const float* soft = soft_old + b * NN;
    float* out = soft_new + b * NN;
    int deg = row_deg[m];
    if (deg > MAXD) deg = MAXD;
    const int* cols = row_cols + m * MAXD;

    // Pass 1: sign product + min / second-min of |x| over the row's edges.
    float sgn = 1.0f, mn = 1e30f, sub = 1e30f;
    for (int j = 0; j < deg; ++j) {
        int c = cols[j];
        float x = soft[c];
        float s = (x > 0.0f) ? 1.0f : ((x < 0.0f) ? -1.0f : 0.0f); // jnp.sign
        sgn *= s;
        float a = fabsf(x);
        if (a < mn) { sub = mn; mn = a; }
        else if (a < sub) { sub = a; }
    }

    // Pass 2: per-edge extrinsic message, scatter-add.
    float c0 = 0.0f, c1 = 0.0f;
    for (int j = 0; j < deg; ++j) {
        int c = cols[j];
        float x = soft[c];
        float s = (x > 0.0f) ? 1.0f : ((x < 0.0f) ? -1.0f : 0.0f);
        float a = fabsf(x);
        float res = (a > mn) ? mn : sub;   // exclude self if self is the min
        float cv = norm * res * sgn * s;   // row_sign * s_self divides out self
        if (c == 0)      c0 += cv;
        else if (c == 1) c1 += cv;
        else             atomicAdd(&out[c], cv);
    }

    // Block-reduce the two all-ones columns.
    __shared__ float r0[256], r1[256];
    r0[threadIdx.x] = c0;
    r1[threadIdx.x] = c1;
    __syncthreads();
    for (int s2 = 128; s2 > 0; s2 >>= 1) {
        if (threadIdx.x < s2) {
            r0[threadIdx.x] += r0[threadIdx.x + s2];
            r1[threadIdx.x] += r1[threadIdx.x + s2];
        }
        __syncthreads();
    }
    if (threadIdx.x == 0) {
        atomicAdd(&out[0], r0[0]);
        atomicAdd(&out[1], r1[0]);
    }
}

extern "C" void kernel_launch(void* const* d_in, const int* in_sizes, int n_in,
                              void* d_out, int out_size, void* d_ws, size_t ws_size,
                              hipStream_t stream) {
    const float* soft_in = (const float*)d_in[0];
    const int*   H       = (const int*)d_in[1];
    // d_in[2] = labels (unused by the forward reference)
    const float* w       = (const float*)d_in[3];
    float* out = (float*)d_out;

    char* ws = (char*)d_ws;
    int*   row_deg  = (int*)ws;                         // 4 KB
    int*   row_cols = (int*)(ws + 4096);                // 256 KB
    float* bufA     = (float*)(ws + 4096 + MM * MAXD * 4);
    float* bufB     = bufA + BB * NN;

    // Preprocess: H -> row edge lists (ws is re-poisoned every call).
    hipMemsetAsync(row_deg, 0, MM * sizeof(int), stream);
    build_rows<<<(MM * NN + 255) / 256, 256, 0, stream>>>(H, row_deg, row_cols);

    const float* src = soft_in;
    for (int it = 0; it < NITER; ++it) {
        float* dst = (it == NITER - 1) ? out : ((it & 1) ? bufB : bufA);
        // soft_new starts as soft_input (the "+ soft_input" marginalization).
        hipMemcpyAsync(dst, soft_in, BB * NN * sizeof(float),
                       hipMemcpyDeviceToDevice, stream);
        check_pass<<<(BB * MM) / 256, 256, 0, stream>>>(src, dst, row_deg, row_cols, w);
        src = dst;
    }
}

// Round 2
// 196.843 us; speedup vs baseline: 1.5569x; 1.5569x over previous
//
#include <hip/hip_runtime.h>

#define BB 16
#define MM 1024
#define NN 2048
#define RCAP 64   // max row degree (mean ~22.5, P(>64) ~ 0)
#define CCAP 48   // max col degree for c>=2 (mean ~10.2, P(>48) ~ 0)
#define NITER 5

// One pass over H: build CSR row lists (all cols) and CSC col lists (cols>=2).
// Cols 0,1 are all-ones by construction (H[:, :2] = 1) -> no list needed.
__global__ void build_lists(const int4* __restrict__ H4,
                            int* __restrict__ row_deg, int* __restrict__ col_deg,
                            unsigned short* __restrict__ row_cols,
                            unsigned short* __restrict__ col_rows) {
    int idx = blockIdx.x * blockDim.x + threadIdx.x;   // M*N/4 threads
    if (idx >= MM * NN / 4) return;
    int4 h = H4[idx];
    int base = idx << 2;
    int m = base >> 11;            // / NN
    int c0 = base & (NN - 1);      // % NN
    int hv[4] = {h.x, h.y, h.z, h.w};
#pragma unroll
    for (int k = 0; k < 4; ++k) {
        if (hv[k]) {
            int c = c0 + k;
            int j = atomicAdd(&row_deg[m], 1);
            if (j < RCAP) row_cols[m * RCAP + j] = (unsigned short)c;
            if (c >= 2) {
                int j2 = atomicAdd(&col_deg[c], 1);
                if (j2 < CCAP) col_rows[c * CCAP + j2] = (unsigned short)m;
            }
        }
    }
}

__device__ __forceinline__ float signf(float x) {
    return (x > 0.0f) ? 1.0f : ((x < 0.0f) ? -1.0f : 0.0f);  // jnp.sign
}

// One block per batch element b. All 5 iterations in LDS; no atomics.
__global__ __launch_bounds__(1024)
void decode(const float* __restrict__ soft_in, float* __restrict__ out,
            const int* __restrict__ row_deg,
            const unsigned short* __restrict__ row_cols,
            const int* __restrict__ col_deg,
            const unsigned short* __restrict__ col_rows,
            const float* __restrict__ wptr) {
    __shared__ float s_soft[NN];    // current soft values
    __shared__ float s_in[NN];      // channel input (the "+ soft_input" term)
    __shared__ float s_sgn[MM];     // norm * product-of-signs per row
    __shared__ float s_mn[MM];      // min |x| per row
    __shared__ float s_sub[MM];     // 2nd-min |x| per row
    __shared__ float s_red[32];     // 16 waves x 2 heavy-col partials

    const int b = blockIdx.x;
    const int t = threadIdx.x;      // 1024 threads
    const int lane = t & 63, wave = t >> 6;
    const float norm = log1pf(expf(wptr[0]));  // softplus(w)

    // Load channel input; init soft = input.
    float i0 = soft_in[b * NN + t], i1 = soft_in[b * NN + t + 1024];
    s_in[t] = i0; s_in[t + 1024] = i1;
    s_soft[t] = i0; s_soft[t + 1024] = i1;

    // Per-thread static metadata.
    const int rdeg = min(row_deg[t], RCAP);                 // my check row m = t
    const unsigned short* rc = row_cols + t * RCAP;
    const int n1 = 2 + t;                                   // my variable cols
    const int n2 = 1026 + t;                                // (guard n2 < NN)
    const int cd1 = min(col_deg[n1], CCAP);
    const int cd2 = (n2 < NN) ? min(col_deg[n2], CCAP) : 0;
    const unsigned short* cl1 = col_rows + n1 * CCAP;
    const unsigned short* cl2 = col_rows + n2 * CCAP;

    __syncthreads();

    for (int it = 0; it < NITER; ++it) {
        // ---- Phase A: row stats (thread = check row m = t) ----
        float sgn = 1.0f, mn = 1e30f, sub = 1e30f;
        for (int j = 0; j < rdeg; ++j) {
            float x = s_soft[rc[j]];
            sgn *= signf(x);
            float a = fabsf(x);
            if (a < mn) { sub = mn; mn = a; }
            else if (a < sub) { sub = a; }
        }
        s_sgn[t] = norm * sgn;   // fold the normalization factor in
        s_mn[t] = mn;
        s_sub[t] = sub;
        __syncthreads();

        // ---- Phase B: variable update (gather over column's rows) ----
        // Heavy cols 0,1 (every row): thread t covers row t.
        float x0 = s_soft[0], x1 = s_soft[1];
        {
            float sg = s_sgn[t], mr = s_mn[t], sr = s_sub[t];
            float a0 = fabsf(x0), a1 = fabsf(x1);
            float cv0 = sg * ((a0 > mr) ? mr : sr) * signf(x0);
            float cv1 = sg * ((a1 > mr) ? mr : sr) * signf(x1);
#pragma unroll
            for (int off = 32; off > 0; off >>= 1) {
                cv0 += __shfl_down(cv0, off);
                cv1 += __shfl_down(cv1, off);
            }
            if (lane == 0) { s_red[wave] = cv0; s_red[16 + wave] = cv1; }
        }
        // Normal cols: gather row stats, no hazards (only owner touches n).
        float v1 = 0.0f, v2 = 0.0f;
        {
            float x = s_soft[n1];
            float a = fabsf(x), sx = signf(x), acc = 0.0f;
            for (int j = 0; j < cd1; ++j) {
                int m = cl1[j];
                float mr = s_mn[m];
                acc += s_sgn[m] * ((a > mr) ? mr : s_sub[m]) * sx;
            }
            v1 = s_in[n1] + acc;
        }
        if (n2 < NN) {
            float x = s_soft[n2];
            float a = fabsf(x), sx = signf(x), acc = 0.0f;
            for (int j = 0; j < cd2; ++j) {
                int m = cl2[j];
                float mr = s_mn[m];
                acc += s_sgn[m] * ((a > mr) ? mr : s_sub[m]) * sx;
            }
            v2 = s_in[n2] + acc;
        }
        __syncthreads();   // all reads of s_soft[0..1] and stats are done

        s_soft[n1] = v1;
        if (n2 < NN) s_soft[n2] = v2;
        if (t == 0) {
            float t0 = 0.0f, t1 = 0.0f;
#pragma unroll
            for (int i = 0; i < 16; ++i) { t0 += s_red[i]; t1 += s_red[16 + i]; }
            s_soft[0] = s_in[0] + t0;
            s_soft[1] = s_in[1] + t1;
        }
        __syncthreads();
    }

    out[b * NN + t] = s_soft[t];
    out[b * NN + t + 1024] = s_soft[t + 1024];
}

extern "C" void kernel_launch(void* const* d_in, const int* in_sizes, int n_in,
                              void* d_out, int out_size, void* d_ws, size_t ws_size,
                              hipStream_t stream) {
    const float* soft_in = (const float*)d_in[0];
    const int*   H       = (const int*)d_in[1];
    // d_in[2] = labels (unused by forward reference)
    const float* w       = (const float*)d_in[3];

    char* ws = (char*)d_ws;
    int* row_deg = (int*)ws;                                  //   4 KB
    int* col_deg = (int*)(ws + 4096);                         //   8 KB
    unsigned short* row_cols = (unsigned short*)(ws + 12288); // 128 KB
    unsigned short* col_rows = (unsigned short*)(ws + 12288 + MM * RCAP * 2); // 192 KB

    hipMemsetAsync(row_deg, 0, 12288, stream);  // row_deg + col_deg together
    build_lists<<<(MM * NN / 4 + 255) / 256, 256, 0, stream>>>(
        (const int4*)H, row_deg, col_deg, row_cols, col_rows);
    decode<<<BB, 1024, 0, stream>>>(soft_in, (float*)d_out,
                                    row_deg, row_cols, col_deg, col_rows, w);
}

// Round 3
// 144.920 us; speedup vs baseline: 2.1148x; 1.3583x over previous
//
#include <hip/hip_runtime.h>

#define BB 16
#define MM 1024
#define NN 2048
#define RCAP 64   // max row degree (mean ~22.5; 64 is ~9 sigma)
#define CCAP 48   // max col degree for c>=2 (mean ~10.2; 48 is ~11 sigma)
#define NITER 5

__device__ __forceinline__ float signf(float x) {
    return (x > 0.0f) ? 1.0f : ((x < 0.0f) ? -1.0f : 0.0f);  // jnp.sign
}

// One pass over H: CSR row lists (all cols) + CSC col lists (cols>=2).
// Cols 0,1 are all-ones by construction (H[:, :2] = 1) -> handled analytically.
__global__ void build_lists(const int4* __restrict__ H4,
                            int* __restrict__ row_deg, int* __restrict__ col_deg,
                            unsigned short* __restrict__ row_cols,
                            unsigned short* __restrict__ col_rows) {
    int idx = blockIdx.x * blockDim.x + threadIdx.x;   // M*N/4 threads
    if (idx >= MM * NN / 4) return;
    int4 h = H4[idx];
    int base = idx << 2;
    int m = base >> 11;            // / NN
    int c0 = base & (NN - 1);      // % NN
    int hv[4] = {h.x, h.y, h.z, h.w};
#pragma unroll
    for (int k = 0; k < 4; ++k) {
        if (hv[k]) {
            int c = c0 + k;
            int j = atomicAdd(&row_deg[m], 1);
            if (j < RCAP) row_cols[m * RCAP + j] = (unsigned short)c;
            if (c >= 2) {
                int j2 = atomicAdd(&col_deg[c], 1);
                if (j2 < CCAP) col_rows[c * CCAP + j2] = (unsigned short)m;
            }
        }
    }
}

// Check-node update. Grid: 64 blocks = 16 b x 4 row-chunks, 256 threads.
// Writes per-row stats {norm*sign, min, 2nd-min} and accumulates the two
// all-ones columns' cv sums (block-reduced, 2 atomics per block).
__global__ __launch_bounds__(256)
void phase_a(const float* __restrict__ src,             // [B][N] current soft
             const int* __restrict__ row_deg,
             const unsigned short* __restrict__ row_cols,
             float4* __restrict__ stats,                 // [B][M]
             float* __restrict__ heavy,                  // [B][2], this iter's slot
             const float* __restrict__ wptr) {
    __shared__ float s_soft[NN];
    __shared__ float s_red[8];                           // 4 waves x 2 cols
    const int b = blockIdx.x >> 2;
    const int m = ((blockIdx.x & 3) << 8) + threadIdx.x;
    const float norm = log1pf(expf(wptr[0]));            // softplus(w)

    // Stage b's soft vector (8 KB) coalesced.
    const float4* src4 = (const float4*)(src + b * NN);
    float4* s4 = (float4*)s_soft;
    s4[threadIdx.x] = src4[threadIdx.x];
    s4[threadIdx.x + 256] = src4[threadIdx.x + 256];
    __syncthreads();

    const int deg = min(row_deg[m], RCAP);
    const unsigned short* rc = row_cols + m * RCAP;
    float sgn = 1.0f, mn = 1e30f, sub = 1e30f;
    for (int j = 0; j < deg; ++j) {
        float x = s_soft[rc[j]];
        sgn *= signf(x);
        float a = fabsf(x);
        if (a < mn) { sub = mn; mn = a; }
        else if (a < sub) { sub = a; }
    }
    const float ns = norm * sgn;
    stats[b * MM + m] = make_float4(ns, mn, sub, 0.0f);

    // cv contributions to the heavy cols 0,1 (present in every row).
    float x0 = s_soft[0], x1 = s_soft[1];
    float cv0 = ns * ((fabsf(x0) > mn) ? mn : sub) * signf(x0);
    float cv1 = ns * ((fabsf(x1) > mn) ? mn : sub) * signf(x1);
#pragma unroll
    for (int off = 32; off > 0; off >>= 1) {
        cv0 += __shfl_down(cv0, off);
        cv1 += __shfl_down(cv1, off);
    }
    const int lane = threadIdx.x & 63, wv = threadIdx.x >> 6;
    if (lane == 0) { s_red[wv] = cv0; s_red[4 + wv] = cv1; }
    __syncthreads();
    if (threadIdx.x == 0) {
        atomicAdd(&heavy[b * 2 + 0], s_red[0] + s_red[1] + s_red[2] + s_red[3]);
        atomicAdd(&heavy[b * 2 + 1], s_red[4] + s_red[5] + s_red[6] + s_red[7]);
    }
}

// Variable-node update. Grid: 128 blocks = 16 b x 8 col-chunks, 256 threads.
// dst[b][n] = soft_in[b][n] + sum over column rows of cv.
__global__ __launch_bounds__(256)
void phase_b(const float* __restrict__ src,             // current soft (self values)
             const float* __restrict__ soft_in,         // channel input
             float* __restrict__ dst,
             const float4* __restrict__ stats,          // [B][M]
             const int* __restrict__ col_deg,
             const unsigned short* __restrict__ col_rows,
             const float* __restrict__ heavy) {         // [B][2], this iter's slot
    __shared__ float4 s_st[MM];                          // 16 KB staged stats
    const int b = blockIdx.x >> 3;
    const int n = ((blockIdx.x & 7) << 8) + threadIdx.x;

    const float4* st = stats + b * MM;
#pragma unroll
    for (int i = 0; i < 4; ++i) s_st[threadIdx.x + 256 * i] = st[threadIdx.x + 256 * i];
    __syncthreads();

    float result;
    if (n >= 2) {
        float x = src[b * NN + n];
        float a = fabsf(x), sx = signf(x), acc = 0.0f;
        int cd = min(col_deg[n], CCAP);
        const unsigned short* cl = col_rows + n * CCAP;
        for (int j = 0; j < cd; ++j) {
            float4 s = s_st[cl[j]];
            acc += s.x * ((a > s.y) ? s.y : s.z) * sx;
        }
        result = soft_in[b * NN + n] + acc;
    } else {
        result = soft_in[b * NN + n] + heavy[b * 2 + n];
    }
    dst[b * NN + n] = result;
}

extern "C" void kernel_launch(void* const* d_in, const int* in_sizes, int n_in,
                              void* d_out, int out_size, void* d_ws, size_t ws_size,
                              hipStream_t stream) {
    const float* soft_in = (const float*)d_in[0];
    const int*   H       = (const int*)d_in[1];
    // d_in[2] = labels (unused by forward reference)
    const float* w       = (const float*)d_in[3];
    float* out = (float*)d_out;

    char* ws = (char*)d_ws;
    int*   row_deg  = (int*)ws;                              //   4 KB
    int*   col_deg  = (int*)(ws + 4096);                     //   8 KB
    float* heavy    = (float*)(ws + 12288);                  //   5*16*2*4 = 640 B (pad to 1 KB)
    unsigned short* row_cols = (unsigned short*)(ws + 13312);            // 128 KB
    unsigned short* col_rows = (unsigned short*)(ws + 13312 + 131072);   // 192 KB
    float4* stats   = (float4*)(ws + 13312 + 131072 + 196608);           // 256 KB
    float*  soft_buf = (float*)(ws + 13312 + 131072 + 196608 + 262144);  // 128 KB

    // Zero degree counters + heavy accumulators (ws is re-poisoned every call).
    hipMemsetAsync(ws, 0, 13312, stream);
    build_lists<<<(MM * NN / 4 + 255) / 256, 256, 0, stream>>>(
        (const int4*)H, row_deg, col_deg, row_cols, col_rows);

    const float* src = soft_in;
    for (int it = 0; it < NITER; ++it) {
        float* hv = heavy + it * BB * 2;
        phase_a<<<64, 256, 0, stream>>>(src, row_deg, row_cols, stats, hv, w);
        float* dst = (it == NITER - 1) ? out : soft_buf;
        phase_b<<<128, 256, 0, stream>>>(src, soft_in, dst, stats, col_deg, col_rows, hv);
        src = dst;
    }
}